// Round 4
// baseline (3184.918 us; speedup 1.0000x reference)
//
#include <hip/hip_runtime.h>
#include <cstdint>
#include <cstddef>

static constexpr int TT = 1024;   // time steps
static constexpr int BB = 32;     // batch
static constexpr int CC = 256;    // channels (= 2H)
static constexpr int HH = 128;    // hidden per direction
static constexpr int GG = 512;    // 4H gates
static constexpr int MM = TT * BB;

__device__ __forceinline__ float fsig(float x) { return 1.f / (1.f + __expf(-x)); }
__device__ __forceinline__ float ftanh(float x) {
  float e = __expf(2.f * x);
  return 1.f - 2.f / (e + 1.f);
}

// ---------------- x[B][C][T] -> xs[T][B][C] ----------------
__global__ __launch_bounds__(256) void k_transpose_in(const float* __restrict__ x,
                                                      float* __restrict__ xs) {
  __shared__ float tile[32][33];
  const int t0 = blockIdx.x * 32, c0 = blockIdx.y * 32, b = blockIdx.z;
  const int tx = threadIdx.x, ty = threadIdx.y;
#pragma unroll
  for (int i = 0; i < 4; i++) {
    const int cc = ty + i * 8;
    tile[cc][tx] = x[((size_t)b * CC + (c0 + cc)) * TT + t0 + tx];
  }
  __syncthreads();
#pragma unroll
  for (int i = 0; i < 4; i++) {
    const int tt = ty + i * 8;
    xs[((size_t)(t0 + tt) * BB + b) * CC + c0 + tx] = tile[tx][tt];
  }
}

// ---------------- h2[T][B][C] -> out[B][C][T] ----------------
__global__ __launch_bounds__(256) void k_transpose_out(const float* __restrict__ h2,
                                                       float* __restrict__ out) {
  __shared__ float tile[32][33];
  const int t0 = blockIdx.x * 32, c0 = blockIdx.y * 32, b = blockIdx.z;
  const int tx = threadIdx.x, ty = threadIdx.y;
#pragma unroll
  for (int i = 0; i < 4; i++) {
    const int tt = ty + i * 8;
    tile[tt][tx] = h2[((size_t)(t0 + tt) * BB + b) * CC + c0 + tx];
  }
  __syncthreads();
#pragma unroll
  for (int i = 0; i < 4; i++) {
    const int cc = ty + i * 8;
    out[((size_t)b * CC + (c0 + cc)) * TT + t0 + tx] = tile[tx][cc];
  }
}

// ---------------- gx[d][m][g] = X[m][:]·W[d][g][:] + bih[d][g]+bhh[d][g] ----------------
// X: [M][256] row-major.  W: [D][512][256].  Tile: 128(M) x 64(N), K-step 16, 256 threads.
__global__ __launch_bounds__(256) void k_gemm_ih(const float* __restrict__ X,
                                                 const float* __restrict__ W,
                                                 const float* __restrict__ bih,
                                                 const float* __restrict__ bhh,
                                                 float* __restrict__ gx, int M) {
  const int d = blockIdx.z;
  const int row0 = blockIdx.y * 128;
  const int col0 = blockIdx.x * 64;
  const float* Wd = W + (size_t)d * GG * CC;
  __shared__ float As[16][132];  // [k][m], padded
  __shared__ float Ws[16][68];   // [k][n]
  const int tid = threadIdx.x;
  const int tm = tid >> 4;        // 0..15 -> 8 rows each
  const int tn = tid & 15;        // 0..15 -> 4 cols each
  const int lr = tid >> 2;        // 0..63
  const int lk = (tid & 3) * 4;   // 0,4,8,12

  float acc[8][4] = {};
  for (int k0 = 0; k0 < CC; k0 += 16) {
    const float4 a0 = *(const float4*)&X[(size_t)(row0 + lr) * CC + k0 + lk];
    const float4 a1 = *(const float4*)&X[(size_t)(row0 + 64 + lr) * CC + k0 + lk];
    const float4 wv = *(const float4*)&Wd[(size_t)(col0 + lr) * CC + k0 + lk];
    __syncthreads();  // protect LDS from previous iteration's readers
    As[lk + 0][lr] = a0.x; As[lk + 1][lr] = a0.y; As[lk + 2][lr] = a0.z; As[lk + 3][lr] = a0.w;
    As[lk + 0][64 + lr] = a1.x; As[lk + 1][64 + lr] = a1.y; As[lk + 2][64 + lr] = a1.z; As[lk + 3][64 + lr] = a1.w;
    Ws[lk + 0][lr] = wv.x; Ws[lk + 1][lr] = wv.y; Ws[lk + 2][lr] = wv.z; Ws[lk + 3][lr] = wv.w;
    __syncthreads();
#pragma unroll
    for (int kk = 0; kk < 16; kk++) {
      const float4 av0 = *(const float4*)&As[kk][tm * 8];
      const float4 av1 = *(const float4*)&As[kk][tm * 8 + 4];
      const float4 bv = *(const float4*)&Ws[kk][tn * 4];
      const float a[8] = {av0.x, av0.y, av0.z, av0.w, av1.x, av1.y, av1.z, av1.w};
      const float bb4[4] = {bv.x, bv.y, bv.z, bv.w};
#pragma unroll
      for (int i = 0; i < 8; i++)
#pragma unroll
        for (int j = 0; j < 4; j++) acc[i][j] = fmaf(a[i], bb4[j], acc[i][j]);
    }
  }
  float bias[4];
#pragma unroll
  for (int j = 0; j < 4; j++) {
    const int col = col0 + tn * 4 + j;
    bias[j] = bih[d * GG + col] + bhh[d * GG + col];
  }
#pragma unroll
  for (int i = 0; i < 8; i++) {
    const int row = row0 + tm * 8 + i;
    float4 o;
    o.x = acc[i][0] + bias[0];
    o.y = acc[i][1] + bias[1];
    o.z = acc[i][2] + bias[2];
    o.w = acc[i][3] + bias[3];
    *(float4*)&gx[((size_t)d * M + row) * GG + col0 + tn * 4] = o;
  }
}

// ---------------- persistent recurrence: one WG per (d,b) ----------------
// 1024 threads; g = tid&511 (gate row), half = tid>>9 (K-half, WAVE-UNIFORM so every
// h_s ds_read_b128 is a single-address broadcast -> 0 bank conflicts).
// Each thread holds 64 W_hh weights in VGPRs, pinned with opaque asm so the compiler
// cannot rematerialize the loads inside the T-loop (R2/R3 failure: VGPR=52/88).
// gx: [D][T][B][512]; Whh: [D][512][128] (layer base); hout: [T][B][256]
__global__ __launch_bounds__(1024, 4) void k_lstm_rec(const float* __restrict__ gx,
                                                      const float* __restrict__ Whh,
                                                      float* __restrict__ hout) {
  const int b = blockIdx.x & 31;
  const int d = blockIdx.x >> 5;
  const int tid = threadIdx.x;
  const int g = tid & 511;      // gate row 0..511
  const int half = tid >> 9;    // K-half, uniform across each wave
  __shared__ __align__(16) float h_s[HH];
  __shared__ float a_part[2][GG];

  float4 w4[16];  // 64 weights resident in VGPRs
  {
    const float4* wrow = (const float4*)(Whh + ((size_t)d * GG + g) * HH + half * 64);
#pragma unroll
    for (int k = 0; k < 16; k++) w4[k] = wrow[k];
  }
  // Pin: values now defined by asm -> not rematerializable, must stay in VGPRs.
#pragma unroll
  for (int k = 0; k < 16; k++)
    asm volatile("" : "+v"(w4[k].x), "+v"(w4[k].y), "+v"(w4[k].z), "+v"(w4[k].w));

  if (tid < HH) h_s[tid] = 0.f;
  float c = 0.f;

  const float* gxb = gx + ((size_t)d * TT * BB + b) * (size_t)GG;
  const size_t step_stride = (size_t)BB * GG;
  int t = d ? (TT - 1) : 0;
  const int tdir = d ? -1 : 1;
  float gxc = half ? 0.f : gxb[(size_t)t * step_stride + g];
  __syncthreads();

  const float* hbase = h_s + half * 64;
  for (int s = 0; s < TT; s++) {
    // prefetch next step's gx (independent of h) -> hides HBM latency under dot loop
    float gxn = 0.f;
    if (!half && s + 1 < TT) gxn = gxb[(size_t)(t + tdir) * step_stride + g];

    float acc0 = gxc, acc1 = 0.f, acc2 = 0.f, acc3 = 0.f;
#pragma unroll
    for (int k = 0; k < 16; k++) {
      const float4 hv = *(const float4*)&hbase[k * 4];  // single-address wave broadcast
      acc0 = fmaf(w4[k].x, hv.x, acc0);
      acc1 = fmaf(w4[k].y, hv.y, acc1);
      acc2 = fmaf(w4[k].z, hv.z, acc2);
      acc3 = fmaf(w4[k].w, hv.w, acc3);
    }
    a_part[half][g] = (acc0 + acc1) + (acc2 + acc3);
    __syncthreads();

    if (tid < HH) {
      const float i_g = fsig(a_part[0][tid] + a_part[1][tid]);
      const float f_g = fsig(a_part[0][HH + tid] + a_part[1][HH + tid]);
      const float g_g = ftanh(a_part[0][2 * HH + tid] + a_part[1][2 * HH + tid]);
      const float o_g = fsig(a_part[0][3 * HH + tid] + a_part[1][3 * HH + tid]);
      c = f_g * c + i_g * g_g;
      const float h = o_g * ftanh(c);
      h_s[tid] = h;
      hout[((size_t)t * BB + b) * CC + d * HH + tid] = h;
    }
    __syncthreads();  // protects h_s write -> next dot read, and a_part read -> next write
    gxc = gxn;
    t += tdir;
  }
}

extern "C" void kernel_launch(void* const* d_in, const int* in_sizes, int n_in,
                              void* d_out, int out_size, void* d_ws, size_t ws_size,
                              hipStream_t stream) {
  const float* x    = (const float*)d_in[0];
  const float* W_ih = (const float*)d_in[1];  // [2][2][512][256]
  const float* W_hh = (const float*)d_in[2];  // [2][2][512][128]
  const float* b_ih = (const float*)d_in[3];  // [2][2][512]
  const float* b_hh = (const float*)d_in[4];
  float* out = (float*)d_out;

  if (ws_size < (size_t)160 * 1024 * 1024) return;  // need xs(32MiB)+gx(128MiB)

  char* ws = (char*)d_ws;
  float* xs = (float*)ws;                                   // [T][B][C] 32 MiB
  float* gxbuf = (float*)(ws + (size_t)32 * 1024 * 1024);   // [D][M][512] 128 MiB
  float* h1 = out;  // layer-0 hidden staged in d_out (dead before final transpose)
  float* h2 = xs;   // layer-1 hidden reuses xs region (xs dead after layer-0 GEMM)

  const dim3 tb(32, 8);
  const dim3 tg(TT / 32, CC / 32, BB);

  k_transpose_in<<<tg, tb, 0, stream>>>(x, xs);
  k_gemm_ih<<<dim3(GG / 64, MM / 128, 2), 256, 0, stream>>>(xs, W_ih, b_ih, b_hh, gxbuf, MM);
  k_lstm_rec<<<64, 1024, 0, stream>>>(gxbuf, W_hh, h1);
  k_gemm_ih<<<dim3(GG / 64, MM / 128, 2), 256, 0, stream>>>(h1, W_ih + 2 * GG * CC,
                                                            b_ih + 2 * GG, b_hh + 2 * GG, gxbuf, MM);
  k_lstm_rec<<<64, 1024, 0, stream>>>(gxbuf, W_hh + 2 * GG * HH, h2);
  k_transpose_out<<<tg, tb, 0, stream>>>(h2, out);
}

// Round 5
// 2026.471 us; speedup vs baseline: 1.5717x; 1.5717x over previous
//
#include <hip/hip_runtime.h>
#include <cstdint>
#include <cstddef>

static constexpr int TT = 1024;   // time steps
static constexpr int BB = 32;     // batch
static constexpr int CC = 256;    // channels (= 2H)
static constexpr int HH = 128;    // hidden per direction
static constexpr int GG = 512;    // 4H gates
static constexpr int MM = TT * BB;

__device__ __forceinline__ float fsig(float x) { return 1.f / (1.f + __expf(-x)); }
__device__ __forceinline__ float ftanh(float x) {
  float e = __expf(2.f * x);
  return 1.f - 2.f / (e + 1.f);
}

// ---------------- x[B][C][T] -> xs[T][B][C] ----------------
__global__ __launch_bounds__(256) void k_transpose_in(const float* __restrict__ x,
                                                      float* __restrict__ xs) {
  __shared__ float tile[32][33];
  const int t0 = blockIdx.x * 32, c0 = blockIdx.y * 32, b = blockIdx.z;
  const int tx = threadIdx.x, ty = threadIdx.y;
#pragma unroll
  for (int i = 0; i < 4; i++) {
    const int cc = ty + i * 8;
    tile[cc][tx] = x[((size_t)b * CC + (c0 + cc)) * TT + t0 + tx];
  }
  __syncthreads();
#pragma unroll
  for (int i = 0; i < 4; i++) {
    const int tt = ty + i * 8;
    xs[((size_t)(t0 + tt) * BB + b) * CC + c0 + tx] = tile[tx][tt];
  }
}

// ---------------- h2[T][B][C] -> out[B][C][T] ----------------
__global__ __launch_bounds__(256) void k_transpose_out(const float* __restrict__ h2,
                                                       float* __restrict__ out) {
  __shared__ float tile[32][33];
  const int t0 = blockIdx.x * 32, c0 = blockIdx.y * 32, b = blockIdx.z;
  const int tx = threadIdx.x, ty = threadIdx.y;
#pragma unroll
  for (int i = 0; i < 4; i++) {
    const int tt = ty + i * 8;
    tile[tt][tx] = h2[((size_t)(t0 + tt) * BB + b) * CC + c0 + tx];
  }
  __syncthreads();
#pragma unroll
  for (int i = 0; i < 4; i++) {
    const int cc = ty + i * 8;
    out[((size_t)b * CC + (c0 + cc)) * TT + t0 + tx] = tile[tx][cc];
  }
}

// ---------------- gx[d][m][g] = X[m][:]·W[d][g][:] + bih[d][g]+bhh[d][g] ----------------
// X: [M][256] row-major.  W: [D][512][256].  Tile: 128(M) x 64(N), K-step 16, 256 threads.
__global__ __launch_bounds__(256) void k_gemm_ih(const float* __restrict__ X,
                                                 const float* __restrict__ W,
                                                 const float* __restrict__ bih,
                                                 const float* __restrict__ bhh,
                                                 float* __restrict__ gx, int M) {
  const int d = blockIdx.z;
  const int row0 = blockIdx.y * 128;
  const int col0 = blockIdx.x * 64;
  const float* Wd = W + (size_t)d * GG * CC;
  __shared__ float As[16][132];  // [k][m], padded
  __shared__ float Ws[16][68];   // [k][n]
  const int tid = threadIdx.x;
  const int tm = tid >> 4;        // 0..15 -> 8 rows each
  const int tn = tid & 15;        // 0..15 -> 4 cols each
  const int lr = tid >> 2;        // 0..63
  const int lk = (tid & 3) * 4;   // 0,4,8,12

  float acc[8][4] = {};
  for (int k0 = 0; k0 < CC; k0 += 16) {
    const float4 a0 = *(const float4*)&X[(size_t)(row0 + lr) * CC + k0 + lk];
    const float4 a1 = *(const float4*)&X[(size_t)(row0 + 64 + lr) * CC + k0 + lk];
    const float4 wv = *(const float4*)&Wd[(size_t)(col0 + lr) * CC + k0 + lk];
    __syncthreads();  // protect LDS from previous iteration's readers
    As[lk + 0][lr] = a0.x; As[lk + 1][lr] = a0.y; As[lk + 2][lr] = a0.z; As[lk + 3][lr] = a0.w;
    As[lk + 0][64 + lr] = a1.x; As[lk + 1][64 + lr] = a1.y; As[lk + 2][64 + lr] = a1.z; As[lk + 3][64 + lr] = a1.w;
    Ws[lk + 0][lr] = wv.x; Ws[lk + 1][lr] = wv.y; Ws[lk + 2][lr] = wv.z; Ws[lk + 3][lr] = wv.w;
    __syncthreads();
#pragma unroll
    for (int kk = 0; kk < 16; kk++) {
      const float4 av0 = *(const float4*)&As[kk][tm * 8];
      const float4 av1 = *(const float4*)&As[kk][tm * 8 + 4];
      const float4 bv = *(const float4*)&Ws[kk][tn * 4];
      const float a[8] = {av0.x, av0.y, av0.z, av0.w, av1.x, av1.y, av1.z, av1.w};
      const float bb4[4] = {bv.x, bv.y, bv.z, bv.w};
#pragma unroll
      for (int i = 0; i < 8; i++)
#pragma unroll
        for (int j = 0; j < 4; j++) acc[i][j] = fmaf(a[i], bb4[j], acc[i][j]);
    }
  }
  float bias[4];
#pragma unroll
  for (int j = 0; j < 4; j++) {
    const int col = col0 + tn * 4 + j;
    bias[j] = bih[d * GG + col] + bhh[d * GG + col];
  }
#pragma unroll
  for (int i = 0; i < 8; i++) {
    const int row = row0 + tm * 8 + i;
    float4 o;
    o.x = acc[i][0] + bias[0];
    o.y = acc[i][1] + bias[1];
    o.z = acc[i][2] + bias[2];
    o.w = acc[i][3] + bias[3];
    *(float4*)&gx[((size_t)d * M + row) * GG + col0 + tn * 4] = o;
  }
}

// ---------------- persistent recurrence: one WG per (d,b) ----------------
// Diagnosis R2-R4: per-step LDS wave-instruction count was the wall
// (256 uniform ds_read_b128/step ~= 3072 cyc ~= measured 3260 cyc/step).
// New shape: 512 threads; thread (q=tid>>7, j=tid&127) computes ALL 4 gates of h[j]
// over K-quarter q (4 rows x 32 K = 128 weights in VGPRs). LDS per step:
//   dot: 8 uniform b128 reads/wave x 8 waves = 64 insts (was 256)
//   partials: packed part[q][j][4] -> 1 b128 write/thread, 4 b128 reads/act-thread
// gx: [D][T][B][512]; Whh: [D][512][128] (layer base); hout: [T][B][256]
__global__ __launch_bounds__(512, 2) void k_lstm_rec(const float* __restrict__ gx,
                                                     const float* __restrict__ Whh,
                                                     float* __restrict__ hout) {
  const int b = blockIdx.x & 31;
  const int d = blockIdx.x >> 5;
  const int tid = threadIdx.x;
  const int q = tid >> 7;       // K-quarter 0..3 (wave-uniform: waves {0,1}->0, {2,3}->1, ...)
  const int j = tid & 127;      // h index 0..127
  __shared__ __align__(16) float h_s[HH];
  __shared__ __align__(16) float part[4][HH][4];  // [q][j][gate], 8 KiB

  // 4 gates x 32 K weights, register-resident (asm-pinned against remat/sink)
  float4 w4[4][8];
  {
    const float* base = Whh + (size_t)d * GG * HH;
#pragma unroll
    for (int gi = 0; gi < 4; gi++) {
      const float4* wrow = (const float4*)(base + (size_t)(gi * HH + j) * HH + q * 32);
#pragma unroll
      for (int k = 0; k < 8; k++) w4[gi][k] = wrow[k];
    }
  }
#pragma unroll
  for (int gi = 0; gi < 4; gi++)
#pragma unroll
    for (int k = 0; k < 8; k++)
      asm volatile("" : "+v"(w4[gi][k].x), "+v"(w4[gi][k].y), "+v"(w4[gi][k].z), "+v"(w4[gi][k].w));

  if (tid < HH) h_s[tid] = 0.f;
  float c = 0.f;

  const float* gxb = gx + ((size_t)d * TT * BB + b) * (size_t)GG;
  const size_t stride = (size_t)BB * GG;
  int t = d ? (TT - 1) : 0;
  const int tdir = d ? -1 : 1;
  const bool is_act = (tid < HH);  // waves 0-1: activation owners (wave-uniform)

  float gxc0 = 0.f, gxc1 = 0.f, gxc2 = 0.f, gxc3 = 0.f;
  if (is_act) {
    const float* g0 = gxb + (size_t)t * stride + j;
    gxc0 = g0[0]; gxc1 = g0[HH]; gxc2 = g0[2 * HH]; gxc3 = g0[3 * HH];
  }
  __syncthreads();

  for (int s = 0; s < TT; s++) {
    // prefetch next step's gx (independent of h); consumed next iteration
    float gxn0 = 0.f, gxn1 = 0.f, gxn2 = 0.f, gxn3 = 0.f;
    if (is_act && s + 1 < TT) {
      const float* g0 = gxb + (size_t)(t + tdir) * stride + j;
      gxn0 = g0[0]; gxn1 = g0[HH]; gxn2 = g0[2 * HH]; gxn3 = g0[3 * HH];
    }

    // dot: 4 gates over this thread's K-quarter (uniform-address LDS reads)
    const float4* hq = (const float4*)(h_s + q * 32);
    float a0 = 0.f, a1 = 0.f, a2 = 0.f, a3 = 0.f;
#pragma unroll
    for (int k = 0; k < 8; k++) {
      const float4 hv = hq[k];
      a0 = fmaf(w4[0][k].x, hv.x, a0); a0 = fmaf(w4[0][k].y, hv.y, a0);
      a0 = fmaf(w4[0][k].z, hv.z, a0); a0 = fmaf(w4[0][k].w, hv.w, a0);
      a1 = fmaf(w4[1][k].x, hv.x, a1); a1 = fmaf(w4[1][k].y, hv.y, a1);
      a1 = fmaf(w4[1][k].z, hv.z, a1); a1 = fmaf(w4[1][k].w, hv.w, a1);
      a2 = fmaf(w4[2][k].x, hv.x, a2); a2 = fmaf(w4[2][k].y, hv.y, a2);
      a2 = fmaf(w4[2][k].z, hv.z, a2); a2 = fmaf(w4[2][k].w, hv.w, a2);
      a3 = fmaf(w4[3][k].x, hv.x, a3); a3 = fmaf(w4[3][k].y, hv.y, a3);
      a3 = fmaf(w4[3][k].z, hv.z, a3); a3 = fmaf(w4[3][k].w, hv.w, a3);
    }
    *(float4*)&part[q][j][0] = make_float4(a0, a1, a2, a3);
    __syncthreads();

    if (is_act) {
      const float4 p0 = *(const float4*)&part[0][j][0];
      const float4 p1 = *(const float4*)&part[1][j][0];
      const float4 p2 = *(const float4*)&part[2][j][0];
      const float4 p3 = *(const float4*)&part[3][j][0];
      const float i_g = fsig(p0.x + p1.x + p2.x + p3.x + gxc0);
      const float f_g = fsig(p0.y + p1.y + p2.y + p3.y + gxc1);
      const float g_g = ftanh(p0.z + p1.z + p2.z + p3.z + gxc2);
      const float o_g = fsig(p0.w + p1.w + p2.w + p3.w + gxc3);
      c = f_g * c + i_g * g_g;
      const float h = o_g * ftanh(c);
      h_s[j] = h;
      hout[((size_t)t * BB + b) * CC + d * HH + j] = h;
    }
    __syncthreads();  // h_s ready for next dot; part safe to overwrite
    gxc0 = gxn0; gxc1 = gxn1; gxc2 = gxn2; gxc3 = gxn3;
    t += tdir;
  }
}

extern "C" void kernel_launch(void* const* d_in, const int* in_sizes, int n_in,
                              void* d_out, int out_size, void* d_ws, size_t ws_size,
                              hipStream_t stream) {
  const float* x    = (const float*)d_in[0];
  const float* W_ih = (const float*)d_in[1];  // [2][2][512][256]
  const float* W_hh = (const float*)d_in[2];  // [2][2][512][128]
  const float* b_ih = (const float*)d_in[3];  // [2][2][512]
  const float* b_hh = (const float*)d_in[4];
  float* out = (float*)d_out;

  if (ws_size < (size_t)160 * 1024 * 1024) return;  // need xs(32MiB)+gx(128MiB)

  char* ws = (char*)d_ws;
  float* xs = (float*)ws;                                   // [T][B][C] 32 MiB
  float* gxbuf = (float*)(ws + (size_t)32 * 1024 * 1024);   // [D][M][512] 128 MiB
  float* h1 = out;  // layer-0 hidden staged in d_out (dead before final transpose)
  float* h2 = xs;   // layer-1 hidden reuses xs region (xs dead after layer-0 GEMM)

  const dim3 tb(32, 8);
  const dim3 tg(TT / 32, CC / 32, BB);

  k_transpose_in<<<tg, tb, 0, stream>>>(x, xs);
  k_gemm_ih<<<dim3(GG / 64, MM / 128, 2), 256, 0, stream>>>(xs, W_ih, b_ih, b_hh, gxbuf, MM);
  k_lstm_rec<<<64, 512, 0, stream>>>(gxbuf, W_hh, h1);
  k_gemm_ih<<<dim3(GG / 64, MM / 128, 2), 256, 0, stream>>>(h1, W_ih + 2 * GG * CC,
                                                            b_ih + 2 * GG, b_hh + 2 * GG, gxbuf, MM);
  k_lstm_rec<<<64, 512, 0, stream>>>(gxbuf, W_hh + 2 * GG * HH, h2);
  k_transpose_out<<<tg, tb, 0, stream>>>(h2, out);
}